// Round 11
// baseline (313.137 us; speedup 1.0000x reference)
//
#include <hip/hip_runtime.h>

typedef _Float16 h2 __attribute__((ext_vector_type(2)));
typedef _Float16 h4 __attribute__((ext_vector_type(4)));
typedef _Float16 h8 __attribute__((ext_vector_type(8)));
typedef float    f4 __attribute__((ext_vector_type(4)));

#define TT 512
#define NB 512
#define II 32
#define HH 64
#define BT 16          // batch tile per block
#define LROW 72        // padded LDS row (f16 units), 144B: 16B-aligned, 2-way max alias

static __device__ __forceinline__ float fexp2f(float x){ return __builtin_amdgcn_exp2f(x); }
static __device__ __forceinline__ float frcpf(float x){ return __builtin_amdgcn_rcpf(x); }
static __device__ __forceinline__ float sigf(float x){ return frcpf(1.0f + fexp2f(-1.442695040888963f*x)); }
static __device__ __forceinline__ float tanhf_fast(float x){ return 1.0f - 2.0f*frcpf(1.0f + fexp2f(2.885390081777926f*x)); }

struct H8S { h2 a,b,c,d; };
struct H4S { h2 a,b; };
static __device__ __forceinline__ h2 pkrtz(float a, float b){
  return __builtin_bit_cast(h2, __builtin_amdgcn_cvt_pkrtz(a, b));
}
static __device__ __forceinline__ h8 pack8(h2 a, h2 b, h2 c, h2 d){
  H8S s{a,b,c,d}; return __builtin_bit_cast(h8, s);
}
static __device__ __forceinline__ h8 cvt8(float4 a, float4 b){
  return pack8(pkrtz(a.x,a.y), pkrtz(a.z,a.w), pkrtz(b.x,b.y), pkrtz(b.z,b.w));
}
static __device__ __forceinline__ h8 ld8cvt(const float* p){
  return cvt8(((const float4*)p)[0], ((const float4*)p)[1]);
}
static __device__ __forceinline__ f4 mfma16(h8 a, h8 b, f4 c){
  return __builtin_amdgcn_mfma_f32_16x16x32_f16(a, b, c, 0, 0, 0);
}

// Raw barrier: drains LDS ops (h exchange correctness), leaves global loads
// (x prefetch) in flight across phases.
static __device__ __forceinline__ void phase_barrier(){
  asm volatile("s_waitcnt lgkmcnt(0)" ::: "memory");
  __builtin_amdgcn_s_barrier();
  asm volatile("" ::: "memory");
}

// Merged-wave phase: one wave computes L0 step P AND L1 step P-1.
// ba/bb = h0[P-1] is SHARED between L0's h-MFMAs and L1's ih-MFMAs
// (R10 had two wave groups each reading it -> 24 b128/CU/phase, now 16).
// DOL0/DOL1 are compile-time literals at each expansion.
#define GPHASE(DOL0, DOL1, XA, XB, P)                                        \
{                                                                            \
  const _Float16* h0r = &h0L[buf][c*LROW];                                   \
  h8 ba = *(const h8*)(h0r + 8*g);                                           \
  h8 bb = *(const h8*)(h0r + 32 + 8*g);                                      \
  f4 Dr, Dz, Dni, Dnh;                                                       \
  if (DOL1) {                                                                \
    const _Float16* h1r = &h1L[buf][c*LROW];                                 \
    h8 v0 = *(const h8*)(h1r + 8*g);                                         \
    h8 v1 = *(const h8*)(h1r + 32 + 8*g);                                    \
    Dr = brv1; Dz = bzv1; Dni = biv1; Dnh = bhv1;                            \
    Dr  = mfma16(P0[0][0], ba, Dr);   Dr  = mfma16(P0[0][1], bb, Dr);        \
    Dr  = mfma16(P1[0][0], v0, Dr);   Dr  = mfma16(P1[0][1], v1, Dr);        \
    Dz  = mfma16(P0[1][0], ba, Dz);   Dz  = mfma16(P0[1][1], bb, Dz);        \
    Dz  = mfma16(P1[1][0], v0, Dz);   Dz  = mfma16(P1[1][1], v1, Dz);        \
    Dni = mfma16(P0[2][0], ba, Dni);  Dni = mfma16(P0[2][1], bb, Dni);       \
    Dnh = mfma16(P1[2][0], v0, Dnh);  Dnh = mfma16(P1[2][1], v1, Dnh);       \
  }                                                                          \
  if (DOL0) {                                                                \
    h8 bx = cvt8(XA, XB);                                                    \
    f4 Cr = brv0, Cz = bzv0, Cni = biv0, Cnh = bhv0;                         \
    Cr  = mfma16(Ah[0][0], ba, Cr);   Cr  = mfma16(Ah[0][1], bb, Cr);        \
    Cz  = mfma16(Ah[1][0], ba, Cz);   Cz  = mfma16(Ah[1][1], bb, Cz);        \
    Cnh = mfma16(Ah[2][0], ba, Cnh);  Cnh = mfma16(Ah[2][1], bb, Cnh);       \
    Cr  = mfma16(Ax[0], bx, Cr);                                             \
    Cz  = mfma16(Ax[1], bx, Cz);                                             \
    Cni = mfma16(Ax[2], bx, Cni);                                            \
    { const float* pn = xrow + (size_t)(((P)+2 < TT) ? ((P)+2) : (TT-1))*II; \
      XA = ((const float4*)pn)[0];  XB = ((const float4*)pn)[1]; }           \
    _Pragma("unroll")                                                        \
    for (int i = 0; i < 4; ++i){                                             \
      const float r  = sigf(Cr[i]);                                          \
      const float z  = sigf(Cz[i]);                                          \
      const float nn = tanhf_fast(Cni[i] + r*Cnh[i]);                        \
      hp0[i] = nn + z*(hp0[i] - nn);                                         \
    }                                                                        \
    H4S s0{ pkrtz(hp0[0], hp0[1]), pkrtz(hp0[2], hp0[3]) };                  \
    *(h4*)(&h0L[buf^1][c*LROW + j0]) = __builtin_bit_cast(h4, s0);           \
  }                                                                          \
  if (DOL1) {                                                                \
    _Pragma("unroll")                                                        \
    for (int i = 0; i < 4; ++i){                                             \
      const float r  = sigf(Dr[i]);                                          \
      const float z  = sigf(Dz[i]);                                          \
      const float nn = tanhf_fast(Dni[i] + r*Dnh[i]);                        \
      hp1[i] = nn + z*(hp1[i] - nn);                                         \
    }                                                                        \
    H4S s1{ pkrtz(hp1[0], hp1[1]), pkrtz(hp1[2], hp1[3]) };                  \
    *(h4*)(&h1L[buf^1][c*LROW + j0]) = __builtin_bit_cast(h4, s1);           \
  }                                                                          \
  phase_barrier();                                                           \
  buf ^= 1;                                                                  \
}

// 32 blocks x 256 threads (4 waves, 1/SIMD). Wave w owns units [16w,16w+16)
// of BOTH layers; phase p = {L0 step p, L1 step p-1}. In-wave ILP (L0/L1
// chains independent) replaces the TLP of R10's 8-wave split; LDS reads/CU
// drop 24->16 b128; barrier syncs 4 waves. Trans/SIMD invariant at 384 cyc.
__global__ __launch_bounds__(256, 1)
void gru2_merged(
    const float* __restrict__ x,
    const float* __restrict__ Wih0, const float* __restrict__ Whh0,
    const float* __restrict__ bih0, const float* __restrict__ bhh0,
    const float* __restrict__ Wih1, const float* __restrict__ Whh1,
    const float* __restrict__ b_ih1, const float* __restrict__ b_hh1,
    const float* __restrict__ fcw, const float* __restrict__ fcb,
    float* __restrict__ out)
{
  const int tid  = threadIdx.x;
  const int w    = tid >> 6;        // wave 0..3 = unit group
  const int lane = tid & 63;
  const int c    = lane & 15;       // batch within tile
  const int g    = lane >> 4;       // k-group / reg-row group
  const int b0   = blockIdx.x * BT;

  __shared__ _Float16 h0L[2][16*LROW];
  __shared__ _Float16 h1L[2][16*LROW];
  __shared__ float    fcred[256];

  for (int i = tid; i < 16*LROW; i += 256){
    h0L[0][i] = (_Float16)0; h0L[1][i] = (_Float16)0;
    h1L[0][i] = (_Float16)0; h1L[1][i] = (_Float16)0;
  }

  // ---- persistent A-frags: BOTH layers' weights for this wave's units ----
  const int r0 = 16*w + c, r1 = 64 + 16*w + c, r2 = 128 + 16*w + c;
  const int j0 = 16*w + 4*g;

  h8 Ax[3];        // L0 x-part (K=32)
  h8 Ah[3][2];     // L0 h-part (K=64)
  h8 P0[3][2];     // L1 ih-part (Wih1)
  h8 P1[3][2];     // L1 hh-part (Whh1)
  Ax[0] = ld8cvt(Wih0 + r0*II + 8*g);
  Ax[1] = ld8cvt(Wih0 + r1*II + 8*g);
  Ax[2] = ld8cvt(Wih0 + r2*II + 8*g);
#pragma unroll
  for (int q = 0; q < 2; ++q){
    Ah[0][q] = ld8cvt(Whh0 + r0*HH + 32*q + 8*g);
    Ah[1][q] = ld8cvt(Whh0 + r1*HH + 32*q + 8*g);
    Ah[2][q] = ld8cvt(Whh0 + r2*HH + 32*q + 8*g);
    P0[0][q] = ld8cvt(Wih1 + r0*HH + 32*q + 8*g);
    P0[1][q] = ld8cvt(Wih1 + r1*HH + 32*q + 8*g);
    P0[2][q] = ld8cvt(Wih1 + r2*HH + 32*q + 8*g);
    P1[0][q] = ld8cvt(Whh1 + r0*HH + 32*q + 8*g);
    P1[1][q] = ld8cvt(Whh1 + r1*HH + 32*q + 8*g);
    P1[2][q] = ld8cvt(Whh1 + r2*HH + 32*q + 8*g);
  }

  f4 brv0, bzv0, biv0, bhv0, brv1, bzv1, biv1, bhv1;
#pragma unroll
  for (int i = 0; i < 4; ++i){
    brv0[i] = bih0[j0+i]      + bhh0[j0+i];
    bzv0[i] = bih0[64+j0+i]   + bhh0[64+j0+i];
    biv0[i] = bih0[128+j0+i];
    bhv0[i] = bhh0[128+j0+i];
    brv1[i] = b_ih1[j0+i]     + b_hh1[j0+i];
    bzv1[i] = b_ih1[64+j0+i]  + b_hh1[64+j0+i];
    biv1[i] = b_ih1[128+j0+i];
    bhv1[i] = b_hh1[128+j0+i];
  }

  float hp0[4] = {0.f,0.f,0.f,0.f};
  float hp1[4] = {0.f,0.f,0.f,0.f};

  // parity-buffer depth-2 x prefetch: even phases use x0*, odd use x1*.
  // No register shifting -> the wait for a load lands 2 full phases later.
  const float* xrow = x + (size_t)(b0+c)*TT*II + 8*g;
  float4 x0a, x0b, x1a, x1b;
  x0a = ((const float4*)xrow)[0];       x0b = ((const float4*)xrow)[1];
  x1a = ((const float4*)(xrow+II))[0];  x1b = ((const float4*)(xrow+II))[1];

  int buf = 0;
  __syncthreads();

  // phase 0: L0 only (even parity)
  GPHASE(true, false, x0a, x0b, 0);
  // phases 1..510 (255 iterations x 2 phases)
  for (int p = 1; p < TT-1; p += 2){
    GPHASE(true, true, x1a, x1b, p);       // odd
    GPHASE(true, true, x0a, x0b, p+1);     // even
  }
  // phase 511 (odd): L0 last step + L1 step 510
  GPHASE(true, true, x1a, x1b, TT-1);
  // phase 512: L1 only (step 511)
  GPHASE(false, true, x0a, x0b, 0);

  // ---- FC epilogue: hp1 = h1[511] for this wave's units ----
  {
    float s = fcw[j0]*hp1[0] + fcw[j0+1]*hp1[1] + fcw[j0+2]*hp1[2] + fcw[j0+3]*hp1[3];
    fcred[(w*4 + g)*16 + c] = s;
  }
  __syncthreads();
  if (tid < 16){
    float s = fcb[0];
#pragma unroll
    for (int q = 0; q < 16; ++q) s += fcred[q*16 + tid];
    out[b0 + tid] = s;
  }
}

extern "C" void kernel_launch(void* const* d_in, const int* in_sizes, int n_in,
                              void* d_out, int out_size, void* d_ws, size_t ws_size,
                              hipStream_t stream) {
  const float* x    = (const float*)d_in[0];
  const float* Wih0 = (const float*)d_in[1];
  const float* Whh0 = (const float*)d_in[2];
  const float* bih0 = (const float*)d_in[3];
  const float* bhh0 = (const float*)d_in[4];
  const float* Wih1 = (const float*)d_in[5];
  const float* Whh1 = (const float*)d_in[6];
  const float* bih1 = (const float*)d_in[7];
  const float* bhh1 = (const float*)d_in[8];
  const float* fcw  = (const float*)d_in[9];
  const float* fcb  = (const float*)d_in[10];
  float* out = (float*)d_out;

  gru2_merged<<<dim3(NB/BT), dim3(256), 0, stream>>>(
      x, Wih0, Whh0, bih0, bhh0, Wih1, Whh1, bih1, bhh1, fcw, fcb, out);
}